// Round 10
// baseline (231.854 us; speedup 1.0000x reference)
//
#include <hip/hip_runtime.h>

// Problem constants (B=16, D=128, H=32, W=32, K=8192)
#define D 128
#define HW 1024
#define NROWS 16384
#define K 8192

// d_out layout (float offsets): z_q_st | indices | new_codebook | new_count | new_weight
#define OUT0 0
#define OUT1 2097152
#define OUT2 2113536
#define OUT3 3162112
#define OUT4 3170304

typedef __attribute__((ext_vector_type(8))) _Float16 half8;
typedef __attribute__((ext_vector_type(16))) float f32x16;
typedef unsigned short u16;
typedef unsigned long long u64;

// ---- prep: 512 blocks, codebook-split + cnorm + dw-zero + packed/counts init ----
// B layout: [unit g(128)][ Bh: [kk(16)][col(64)][j(8)] | Bl: same ] (32 KiB/unit)
__global__ __launch_bounds__(256) void k_prep(const float* __restrict__ cb,
                                              u16* __restrict__ Bg,
                                              float* __restrict__ cnorm,
                                              u64* __restrict__ packed,
                                              float* __restrict__ counts,
                                              float* __restrict__ dw) {
    const int tid = threadIdx.x;
    int kk = tid & 15;
    int k = blockIdx.x * 16 + (tid >> 4);
    const float* src = cb + (size_t)k * D + kk * 8;
    half8 h, l;
    float s = 0.f;
#pragma unroll
    for (int j = 0; j < 8; ++j) {
        float v = src[j];
        s += v * v;
        _Float16 hv = (_Float16)v;              // RN f32->f16
        _Float16 lv = (_Float16)(v - (float)hv);
        h[j] = hv;
        l[j] = lv;
    }
    int g = k >> 6, col = k & 63;
    size_t offH = (size_t)g * 16384 + ((size_t)kk * 64 + col) * 8;
    *(half8*)((_Float16*)Bg + offH) = h;
    *(half8*)((_Float16*)Bg + offH + 8192) = l;
#pragma unroll
    for (int off = 8; off > 0; off >>= 1) s += __shfl_down(s, off);
    if (kk == 0) cnorm[k] = s;
    // zero dw: 131072 threads x 8 floats = K*D exactly
    float4 z4 = {0.f, 0.f, 0.f, 0.f};
    size_t zi = ((size_t)blockIdx.x * 256 + tid) * 8;
    *(float4*)(dw + zi) = z4;
    *(float4*)(dw + zi + 4) = z4;
    // packed sentinel + counts zero (131072 threads cover NROWS and K)
    int gid = blockIdx.x * 256 + tid;
    if (gid < NROWS) packed[gid] = ~0ull;       // +inf sentinel
    if (gid < K) counts[gid] = 0.f;
}

// ---- main: 3-pass fp16-split distance GEMM + fused argmin, NO-LDS free-run ----
// R10: six rounds of LDS/barrier variants all pinned MfmaUtil at 37-45% -- the
// barrier lockstep is the plateau. B is L2-RESIDENT by construction (each
// XCD's ksplit slice is 1 MB; default bid->XCD round-robin pins bid&3 per
// XCD), so staging it through LDS was pure overhead (Common-mistake #7).
// Each wave free-runs over 32 rows x its 2048-col ksplit in 32-col steps:
// 16 coalesced 512B wave-loads straight from global (L1/L2; 4 waves/block
// read IDENTICAL addresses -> L1 broadcast) + 24 MFMA + fold. No LDS, no
// barriers, no waitcnt games -- latency hidden by 16-load ILP bursts and
// 8 de-phased waves/CU. Acc split accA/accB as verified in R2 (same absmax).
__global__ __launch_bounds__(256, 2) void k_argmin_mfma(
        const float* __restrict__ z_e,
        const u16* __restrict__ Bg,
        const float* __restrict__ cnorm, u64* __restrict__ packed) {
    const int tid = threadIdx.x;
    const int ln  = tid & 63;
    const int l31 = ln & 31;
    const int lh  = ln >> 5;                    // k-half select within frag
    const int wy  = tid >> 6;                   // wave 0..3 = row band

    const int rg = blockIdx.x >> 2;             // 128 row groups x 128 rows
    const int k0 = (blockIdx.x & 3) * 2048;     // k split (XCD-pinned by default map)
    const int band = rg * 4 + wy;               // global 32-row band 0..511

    // ---- A fragments: read this lane's row from z_e (f32, coalesced across
    // lanes) and fp16-split in-register; bit-identical to R8/R9 ----
    const int row = band * 32 + l31;
    const float* zrow = z_e + ((size_t)(row >> 10)) * (D * HW) + (row & 1023);
    half8 Ah[8], Al[8];
#pragma unroll
    for (int ks = 0; ks < 8; ++ks) {
        half8 h, l;
#pragma unroll
        for (int j = 0; j < 8; ++j) {
            float v = zrow[(size_t)(ks * 16 + lh * 8 + j) * HW];
            _Float16 hv = (_Float16)v;          // RN f32->f16
            h[j] = hv;
            l[j] = (_Float16)(v - (float)hv);
        }
        Ah[ks] = h;
        Al[ks] = l;
    }

    const _Float16* Bf = (const _Float16*)Bg;

    float minv[16];
    int   mini[16];
#pragma unroll
    for (int r = 0; r < 16; ++r) { minv[r] = INFINITY; mini[r] = 0; }

    // 64 steps of 32 cols across this block's 2048-col ksplit
#pragma unroll 1
    for (int u = 0; u < 64; ++u) {
        const int c0 = k0 + u * 32 + l31;
        float cn0 = cnorm[c0];

        const int g = (k0 >> 6) + (u >> 1);     // 64-col B-unit
        // fragment base: unit g, col = (u&1)*32 + l31; per-ks stride 512 halfs
        const _Float16* bh = Bf + (size_t)g * 16384 + ((u & 1) * 32 + l31) * 8;
        const _Float16* bl = bh + 8192;

        f32x16 accA = {}, accB = {};
        // pass 1: Ah x Bl -> accA
#pragma unroll
        for (int ks = 0; ks < 8; ++ks) {
            half8 b = *(const half8*)(bl + (ks * 2 + lh) * 512);
            accA = __builtin_amdgcn_mfma_f32_32x32x16_f16(Ah[ks], b, accA, 0, 0, 0);
        }
        // passes 2+3: Ah x Bh -> accB, Al x Bh -> accA (b shared; 2 chains)
#pragma unroll
        for (int ks = 0; ks < 8; ++ks) {
            half8 b = *(const half8*)(bh + (ks * 2 + lh) * 512);
            accB = __builtin_amdgcn_mfma_f32_32x32x16_f16(Ah[ks], b, accB, 0, 0, 0);
            accA = __builtin_amdgcn_mfma_f32_32x32x16_f16(Al[ks], b, accA, 0, 0, 0);
        }

        // fold dist = cnorm - 2*(accA+accB) into running argmin
#pragma unroll
        for (int r = 0; r < 16; ++r) {
            float d0 = fmaf(-2.0f, accA[r] + accB[r], cn0);
            bool p = d0 < minv[r];
            minv[r] = p ? d0 : minv[r];
            mini[r] = p ? c0 : mini[r];
        }
    }

    // ---- reduce across the 32 l31-lanes sharing each output row ----
#pragma unroll
    for (int r = 0; r < 16; ++r) {
        float v = minv[r];
        int ix = mini[r];
#pragma unroll
        for (int off = 1; off < 32; off <<= 1) {
            float v2 = __shfl_xor(v, off);
            int i2 = __shfl_xor(ix, off);
            if (v2 < v || (v2 == v && i2 < ix)) { v = v2; ix = i2; }
        }
        if (l31 == 0) {
            // C/D row map (m74/m101): row = (reg&3) + 8*(reg>>2) + 4*(lane>>5)
            int orow = band * 32 + 4 * lh + (r & 3) + 8 * (r >> 2);
            unsigned int uenc = __float_as_uint(v);
            uenc = (uenc & 0x80000000u) ? ~uenc : (uenc | 0x80000000u);  // monotonic
            u64 pk = ((u64)uenc << 13) | (u64)(unsigned)ix;
            atomicMin(&packed[orow], pk);
        }
    }
}

// ---- epilogue: indices, z_q_st, counts, dw (R9 version, verified) ----
__global__ __launch_bounds__(256) void k_epilogue(const float* __restrict__ z_e,
                                                  const float* __restrict__ cb,
                                                  const u64* __restrict__ packed,
                                                  float* __restrict__ out0,
                                                  float* __restrict__ out1,
                                                  float* __restrict__ counts,
                                                  float* __restrict__ dw) {
    __shared__ float zS[128][33];               // z transposed; stride 33
    __shared__ float cbS[32][129];              // gathered cb rows; stride 129
    __shared__ int idxS[32];
    const int tid = threadIdx.x;
    const int n0 = blockIdx.x * 32;
    const int bb = n0 >> 10, p0 = n0 & 1023;

    if (tid < 32) {
        int ix = (int)(packed[n0 + tid] & 0x1FFFull);
        idxS[tid] = ix;
        out1[n0 + tid] = (float)ix;
        atomicAdd(&counts[ix], 1.0f);
    }
    __syncthreads();

    const float* zb = z_e + (size_t)bb * (D * HW) + p0;
    float* ob = out0 + (size_t)bb * (D * HW) + p0;

    // stage cb rows (one row per 128-thread group -> 256B coalesced reads)
    for (int i = tid; i < 32 * D; i += 256) {
        int row = i >> 7, d = i & 127;
        cbS[row][d] = cb[(size_t)idxS[row] * D + d];
    }
    // stage z (r-inner -> 128B coalesced reads), transposed into zS
    for (int i = tid; i < 32 * D; i += 256) {
        int d = i >> 5, r = i & 31;
        zS[d][r] = zb[(size_t)d * HW + r];
    }
    __syncthreads();
    // z_q_st: coalesced stores; z from zS, c from cbS (both conflict-free)
    for (int i = tid; i < 32 * D; i += 256) {
        int d = i >> 5, r = i & 31;
        float z = zS[d][r];
        float c = cbS[r][d];
        ob[(size_t)d * HW + r] = z + (c - z);
    }
    // dw scatter: one row per 128-thread group -> 256B coalesced atomics
    for (int i = tid; i < 32 * D; i += 256) {
        int r = i >> 7, d = i & 127;
        atomicAdd(&dw[(size_t)idxS[r] * D + d], zS[d][r]);
    }
}

// ---- final: EMA update, float4-vectorized (R9 version, verified) ----
__global__ __launch_bounds__(256) void k_final(const float* __restrict__ ema_count,
                                               const float* __restrict__ ema_weight,
                                               float* __restrict__ out2,
                                               float* __restrict__ out3,
                                               float* __restrict__ out4) {
    int gid = blockIdx.x * 256 + threadIdx.x;   // over K*D/4
    int k = gid >> 5, d4 = gid & 31;
    float cnt_raw = out3[k];
    float4 dw4 = *(const float4*)(out4 + (size_t)gid * 4);
    float4 ew4 = *(const float4*)(ema_weight + (size_t)gid * 4);
    float ec = ema_count[k];
    __syncthreads();                            // out3[k] read-before-write (in-block)
    float nc = 0.99f * ec + 0.01f * cnt_raw;
    float den = fmaxf(nc, 1.0f);
    float4 nw, o2;
    nw.x = 0.99f * ew4.x + 0.01f * dw4.x;  o2.x = nw.x / den;
    nw.y = 0.99f * ew4.y + 0.01f * dw4.y;  o2.y = nw.y / den;
    nw.z = 0.99f * ew4.z + 0.01f * dw4.z;  o2.z = nw.z / den;
    nw.w = 0.99f * ew4.w + 0.01f * dw4.w;  o2.w = nw.w / den;
    *(float4*)(out4 + (size_t)gid * 4) = nw;
    *(float4*)(out2 + (size_t)gid * 4) = o2;
    if (d4 == 0) out3[k] = nc;
}

extern "C" void kernel_launch(void* const* d_in, const int* in_sizes, int n_in,
                              void* d_out, int out_size, void* d_ws, size_t ws_size,
                              hipStream_t stream) {
    const float* z_e        = (const float*)d_in[0];
    const float* cb         = (const float*)d_in[1];
    const float* ema_count  = (const float*)d_in[2];
    const float* ema_weight = (const float*)d_in[3];
    float* out = (float*)d_out;

    float* cnorm = (float*)d_ws;                                   // K floats
    u64* packed = (u64*)((char*)d_ws + K * 4);                     // NROWS u64

    // B-split scratch lives in out2 (4 MB), rewritten later by k_final.
    u16* Bg = (u16*)(out + OUT2);                                  // 128 units x 32 KiB

    k_prep       <<<512,               256, 0, stream>>>(cb, Bg, cnorm,
                                                         packed, out + OUT3, out + OUT4);
    k_argmin_mfma<<<512,               256, 0, stream>>>(z_e, Bg, cnorm, packed);
    k_epilogue   <<<NROWS / 32,        256, 0, stream>>>(z_e, cb, packed,
                                                         out + OUT0, out + OUT1,
                                                         out + OUT3, out + OUT4);
    k_final      <<<(K * D / 4) / 256, 256, 0, stream>>>(ema_count, ema_weight,
                                                         out + OUT2, out + OUT3, out + OUT4);
}

// Round 11
// 202.307 us; speedup vs baseline: 1.1461x; 1.1461x over previous
//
#include <hip/hip_runtime.h>

// Problem constants (B=16, D=128, H=32, W=32, K=8192)
#define D 128
#define HW 1024
#define NROWS 16384
#define K 8192
#define NU 32   // 64-col units per block (2048-col k-split / 64)

// d_out layout (float offsets): z_q_st | indices | new_codebook | new_count | new_weight
#define OUT0 0
#define OUT1 2097152
#define OUT2 2113536
#define OUT3 3162112
#define OUT4 3170304

typedef __attribute__((ext_vector_type(8))) _Float16 half8;
typedef __attribute__((ext_vector_type(16))) float f32x16;
typedef unsigned short u16;
typedef unsigned long long u64;

// ---- async global->LDS, 16B per lane (dst = wave-uniform base + lane*16) ----
__device__ __forceinline__ void gld16(const u16* gsrc, u16* ldst) {
    __builtin_amdgcn_global_load_lds(
        (const __attribute__((address_space(1))) unsigned int*)gsrc,
        (__attribute__((address_space(3))) unsigned int*)ldst,
        16, 0, 0);
}

// ---- prep: 512 blocks, codebook-split + cnorm + dw-zero + packed/counts init ----
// B layout: [unit g(128)][ Bh: [kk(16)][col(64)][j(8)] | Bl: same ] (32 KiB/unit)
__global__ __launch_bounds__(256) void k_prep(const float* __restrict__ cb,
                                              u16* __restrict__ Bg,
                                              float* __restrict__ cnorm,
                                              u64* __restrict__ packed,
                                              float* __restrict__ counts,
                                              float* __restrict__ dw) {
    const int tid = threadIdx.x;
    int kk = tid & 15;
    int k = blockIdx.x * 16 + (tid >> 4);
    const float* src = cb + (size_t)k * D + kk * 8;
    half8 h, l;
    float s = 0.f;
#pragma unroll
    for (int j = 0; j < 8; ++j) {
        float v = src[j];
        s += v * v;
        _Float16 hv = (_Float16)v;              // RN f32->f16
        _Float16 lv = (_Float16)(v - (float)hv);
        h[j] = hv;
        l[j] = lv;
    }
    int g = k >> 6, col = k & 63;
    size_t offH = (size_t)g * 16384 + ((size_t)kk * 64 + col) * 8;
    *(half8*)((_Float16*)Bg + offH) = h;
    *(half8*)((_Float16*)Bg + offH + 8192) = l;
#pragma unroll
    for (int off = 8; off > 0; off >>= 1) s += __shfl_down(s, off);
    if (kk == 0) cnorm[k] = s;
    // zero dw: 131072 threads x 8 floats = K*D exactly
    float4 z4 = {0.f, 0.f, 0.f, 0.f};
    size_t zi = ((size_t)blockIdx.x * 256 + tid) * 8;
    *(float4*)(dw + zi) = z4;
    *(float4*)(dw + zi + 4) = z4;
    // packed sentinel + counts zero (131072 threads cover NROWS and K)
    int gid = blockIdx.x * 256 + tid;
    if (gid < NROWS) packed[gid] = ~0ull;       // +inf sentinel
    if (gid < K) counts[gid] = 0.f;
}

// ---- main: 3-pass fp16-split distance GEMM + fused argmin (R0 structure) ----
// grid: 128 rowgroups x 4 ksplits, 512 threads (8 waves: wy 0..3 x wx 0..1).
// Wave tile: 32 rows x 32 cols; A-frags pinned in VGPRs (converted in-kernel
// from z_e f32 -- R8 fusion); B in 64-col units, 2x32 KiB LDS dbuf
// (2 blocks/CU) with in-flight prefetch across raw s_barrier via vmcnt(4).
// VERIFIED at 106.7-108.5 us / MfmaUtil 44-46%. Plateau confirmed by EIGHT
// failed variants (R1 occupancy, R2 ILP, R4 phase-split, R5 ratio, R6 hoist,
// R7 fold ping-pong, R10 no-LDS/L2-direct: 158us, MfmaUtil 27 -- LDS staging
// is what converts ~200cy L2 latency into pipe throughput). DO NOT TOUCH.
__global__ __launch_bounds__(512, 4) void k_argmin_mfma(
        const float* __restrict__ z_e,
        const u16* __restrict__ Bg,
        const float* __restrict__ cnorm, u64* __restrict__ packed) {
    __shared__ u16 lds[2][16384];               // 2 x 32 KiB

    const int tid = threadIdx.x;
    const int ln  = tid & 63;
    const int l31 = ln & 31;
    const int lh  = ln >> 5;                    // k-half select within frag
    const int wv  = tid >> 6;                   // 0..7
    const int wy  = wv & 3;                     // row band 0..3
    const int wx  = wv >> 2;                    // col half 0..1

    const int rg = blockIdx.x >> 2;             // 128 row groups x 128 rows
    const int k0 = (blockIdx.x & 3) * 2048;     // k split
    const int g0 = k0 >> 6;                     // first 64-col B-unit

    // ---- A fragments: read this lane's row from z_e (f32, coalesced across
    // lanes) and fp16-split in-register; bit-identical to the old prep pass ----
    const int row = (rg * 4 + wy) * 32 + l31;
    const float* zrow = z_e + ((size_t)(row >> 10)) * (D * HW) + (row & 1023);
    half8 Ah[8], Al[8];
#pragma unroll
    for (int ks = 0; ks < 8; ++ks) {
        half8 h, l;
#pragma unroll
        for (int j = 0; j < 8; ++j) {
            float v = zrow[(size_t)(ks * 16 + lh * 8 + j) * HW];
            _Float16 hv = (_Float16)v;          // RN f32->f16
            h[j] = hv;
            l[j] = (_Float16)(v - (float)hv);
        }
        Ah[ks] = h;
        Al[ks] = l;
    }

    // ---- prologue: stage unit 0 (32 KiB, 4 gld16/thread) ----
    {
        const u16* src = Bg + (size_t)g0 * 16384;
#pragma unroll
        for (int r = 0; r < 4; ++r)
            gld16(src + ((size_t)r * 512 + tid) * 8, lds[0] + (r * 512 + tid) * 8);
    }

    float minv[16];
    int   mini[16];
#pragma unroll
    for (int r = 0; r < 16; ++r) { minv[r] = INFINITY; mini[r] = 0; }

#pragma unroll 1
    for (int u = 0; u < NU; ++u) {
        const u16* buf = lds[u & 1];
        const int c0 = k0 + u * 64 + wx * 32 + l31;

        // cn load first (older than the prefetch -> completed once vmcnt<=4)
        float cn0 = cnorm[c0];

        if (u + 1 < NU) {
            const u16* src = Bg + (size_t)(g0 + u + 1) * 16384;
            u16* dst = lds[(u + 1) & 1];
#pragma unroll
            for (int r = 0; r < 4; ++r)
                gld16(src + ((size_t)r * 512 + tid) * 8, dst + (r * 512 + tid) * 8);
            // wait for *this* unit's stage; next unit's 4 loads stay in flight
            asm volatile("s_waitcnt vmcnt(4)" ::: "memory");
        } else {
            asm volatile("s_waitcnt vmcnt(0)" ::: "memory");
        }
        asm volatile("s_barrier" ::: "memory");

        f32x16 acc = {};
        const _Float16* bh = (const _Float16*)buf;
        const _Float16* bl = bh + 8192;

        // pass 1: Ah x Bl
#pragma unroll
        for (int ks = 0; ks < 8; ++ks) {
            const int bo = ((ks * 2 + lh) * 64 + wx * 32 + l31) * 8;
            half8 b0 = *(const half8*)(bl + bo);
            acc = __builtin_amdgcn_mfma_f32_32x32x16_f16(Ah[ks], b0, acc, 0, 0, 0);
        }
        // passes 2+3: Ah x Bh, Al x Bh (B-frag shared)
#pragma unroll
        for (int ks = 0; ks < 8; ++ks) {
            const int bo = ((ks * 2 + lh) * 64 + wx * 32 + l31) * 8;
            half8 b0 = *(const half8*)(bh + bo);
            acc = __builtin_amdgcn_mfma_f32_32x32x16_f16(Ah[ks], b0, acc, 0, 0, 0);
            acc = __builtin_amdgcn_mfma_f32_32x32x16_f16(Al[ks], b0, acc, 0, 0, 0);
        }

        // fold dist = cnorm - 2*dot into running argmin
#pragma unroll
        for (int r = 0; r < 16; ++r) {
            float d0 = fmaf(-2.0f, acc[r], cn0);
            if (d0 < minv[r]) { minv[r] = d0; mini[r] = c0; }
        }
        // all waves done reading buf before its sibling is overwritten next iter
        asm volatile("s_barrier" ::: "memory");
    }

    // ---- reduce across the 32 l31-lanes sharing each output row ----
#pragma unroll
    for (int r = 0; r < 16; ++r) {
        float v = minv[r];
        int ix = mini[r];
#pragma unroll
        for (int off = 1; off < 32; off <<= 1) {
            float v2 = __shfl_xor(v, off);
            int i2 = __shfl_xor(ix, off);
            if (v2 < v || (v2 == v && i2 < ix)) { v = v2; ix = i2; }
        }
        if (l31 == 0) {
            // C/D row map (m74/m101): row = (reg&3) + 8*(reg>>2) + 4*(lane>>5)
            int orow = rg * 128 + wy * 32 + 4 * lh + (r & 3) + 8 * (r >> 2);
            unsigned int uenc = __float_as_uint(v);
            uenc = (uenc & 0x80000000u) ? ~uenc : (uenc | 0x80000000u);  // monotonic
            u64 pk = ((u64)uenc << 13) | (u64)(unsigned)ix;
            atomicMin(&packed[orow], pk);
        }
    }
}

// ---- epilogue: indices, z_q_st, counts, dw (R9 version, verified) ----
__global__ __launch_bounds__(256) void k_epilogue(const float* __restrict__ z_e,
                                                  const float* __restrict__ cb,
                                                  const u64* __restrict__ packed,
                                                  float* __restrict__ out0,
                                                  float* __restrict__ out1,
                                                  float* __restrict__ counts,
                                                  float* __restrict__ dw) {
    __shared__ float zS[128][33];               // z transposed; stride 33
    __shared__ float cbS[32][129];              // gathered cb rows; stride 129
    __shared__ int idxS[32];
    const int tid = threadIdx.x;
    const int n0 = blockIdx.x * 32;
    const int bb = n0 >> 10, p0 = n0 & 1023;

    if (tid < 32) {
        int ix = (int)(packed[n0 + tid] & 0x1FFFull);
        idxS[tid] = ix;
        out1[n0 + tid] = (float)ix;
        atomicAdd(&counts[ix], 1.0f);
    }
    __syncthreads();

    const float* zb = z_e + (size_t)bb * (D * HW) + p0;
    float* ob = out0 + (size_t)bb * (D * HW) + p0;

    // stage cb rows (one row per 128-thread group -> 256B coalesced reads)
    for (int i = tid; i < 32 * D; i += 256) {
        int row = i >> 7, d = i & 127;
        cbS[row][d] = cb[(size_t)idxS[row] * D + d];
    }
    // stage z (r-inner -> 128B coalesced reads), transposed into zS
    for (int i = tid; i < 32 * D; i += 256) {
        int d = i >> 5, r = i & 31;
        zS[d][r] = zb[(size_t)d * HW + r];
    }
    __syncthreads();
    // z_q_st: coalesced stores; z from zS, c from cbS (both conflict-free)
    for (int i = tid; i < 32 * D; i += 256) {
        int d = i >> 5, r = i & 31;
        float z = zS[d][r];
        float c = cbS[r][d];
        ob[(size_t)d * HW + r] = z + (c - z);
    }
    // dw scatter: one row per 128-thread group -> 256B coalesced atomics
    for (int i = tid; i < 32 * D; i += 256) {
        int r = i >> 7, d = i & 127;
        atomicAdd(&dw[(size_t)idxS[r] * D + d], zS[d][r]);
    }
}

// ---- final: EMA update, float4-vectorized (R9 version, verified) ----
__global__ __launch_bounds__(256) void k_final(const float* __restrict__ ema_count,
                                               const float* __restrict__ ema_weight,
                                               float* __restrict__ out2,
                                               float* __restrict__ out3,
                                               float* __restrict__ out4) {
    int gid = blockIdx.x * 256 + threadIdx.x;   // over K*D/4
    int k = gid >> 5, d4 = gid & 31;
    float cnt_raw = out3[k];
    float4 dw4 = *(const float4*)(out4 + (size_t)gid * 4);
    float4 ew4 = *(const float4*)(ema_weight + (size_t)gid * 4);
    float ec = ema_count[k];
    __syncthreads();                            // out3[k] read-before-write (in-block)
    float nc = 0.99f * ec + 0.01f * cnt_raw;
    float den = fmaxf(nc, 1.0f);
    float4 nw, o2;
    nw.x = 0.99f * ew4.x + 0.01f * dw4.x;  o2.x = nw.x / den;
    nw.y = 0.99f * ew4.y + 0.01f * dw4.y;  o2.y = nw.y / den;
    nw.z = 0.99f * ew4.z + 0.01f * dw4.z;  o2.z = nw.z / den;
    nw.w = 0.99f * ew4.w + 0.01f * dw4.w;  o2.w = nw.w / den;
    *(float4*)(out4 + (size_t)gid * 4) = nw;
    *(float4*)(out2 + (size_t)gid * 4) = o2;
    if (d4 == 0) out3[k] = nc;
}

extern "C" void kernel_launch(void* const* d_in, const int* in_sizes, int n_in,
                              void* d_out, int out_size, void* d_ws, size_t ws_size,
                              hipStream_t stream) {
    const float* z_e        = (const float*)d_in[0];
    const float* cb         = (const float*)d_in[1];
    const float* ema_count  = (const float*)d_in[2];
    const float* ema_weight = (const float*)d_in[3];
    float* out = (float*)d_out;

    float* cnorm = (float*)d_ws;                                   // K floats
    u64* packed = (u64*)((char*)d_ws + K * 4);                     // NROWS u64

    // B-split scratch lives in out2 (4 MB), rewritten later by k_final.
    u16* Bg = (u16*)(out + OUT2);                                  // 128 units x 32 KiB

    k_prep       <<<512,               256, 0, stream>>>(cb, Bg, cnorm,
                                                         packed, out + OUT3, out + OUT4);
    k_argmin_mfma<<<512,               512, 0, stream>>>(z_e, Bg, cnorm, packed);
    k_epilogue   <<<NROWS / 32,        256, 0, stream>>>(z_e, cb, packed,
                                                         out + OUT0, out + OUT1,
                                                         out + OUT3, out + OUT4);
    k_final      <<<(K * D / 4) / 256, 256, 0, stream>>>(ema_count, ema_weight,
                                                         out + OUT2, out + OUT3, out + OUT4);
}